// Round 1
// baseline (212.349 us; speedup 1.0000x reference)
//
#include <hip/hip_runtime.h>
#include <hip/hip_bf16.h>

#define HH   512
#define BB   8192
#define WIDTH (1.0f/16.0f)

typedef __attribute__((ext_vector_type(8))) short  short8;   // 8 bf16 = 4 VGPRs
typedef __attribute__((ext_vector_type(4))) float  floatx4;

typedef const __attribute__((address_space(1))) void* gptr_t;
typedef __attribute__((address_space(3))) void*       lptr_t;

__device__ __forceinline__ void gload_lds16(const void* g, void* l) {
    // async global->LDS, 16B per lane; LDS dst = wave-uniform base + lane*16
    __builtin_amdgcn_global_load_lds((gptr_t)g, (lptr_t)l, 16, 0, 0);
}

__device__ __forceinline__ float tanh_fast(float x) {
    float e = __expf(2.0f * x);
    return 1.0f - 2.0f * __builtin_amdgcn_rcpf(e + 1.0f);
}

// ---- prep_all: W2 transpose | W1 transpose | prep_v + ldout init, one dispatch ----
__global__ void prep_all(const float* __restrict__ vin, const float* __restrict__ W1,
                         const float* __restrict__ W2, const float* __restrict__ ld,
                         float* __restrict__ vout, float* __restrict__ ldout,
                         __hip_bfloat16* __restrict__ Abf,
                         __hip_bfloat16* __restrict__ W1T,
                         __hip_bfloat16* __restrict__ W2T) {
    __shared__ float tile[32][33];
    int bid = blockIdx.x, tid = threadIdx.x;
    if (bid < 4352) {
        // transpose branch: W2 (512x8192) for bid<4096, else W1 (512x512)
        const float* src;  __hip_bfloat16* dst;  int cols, c0, r0;
        if (bid < 4096) { src = W2; dst = W2T; cols = 8192; c0 = (bid & 255) * 32; r0 = (bid >> 8) * 32; }
        else            { int b = bid - 4096; src = W1; dst = W1T; cols = 512; c0 = (b & 15) * 32; r0 = (b >> 4) * 32; }
        int x = tid & 31, y = tid >> 5;            // (32,8) logical
        #pragma unroll
        for (int i = 0; i < 32; i += 8)
            tile[y + i][x] = src[(size_t)(r0 + y + i) * cols + c0 + x];
        __syncthreads();
        #pragma unroll
        for (int i = 0; i < 32; i += 8)
            dst[(size_t)(c0 + y + i) * 512 + r0 + x] = __float2bfloat16(tile[x][y + i]);
    } else {
        // prep_v branch: v_out[:, :512] = v_in[:, :512]; Abf = bf16(v_p - 0.5); ldout = ld
        int b = bid - 4352;                        // 0..2047
        int i = b * 256 + tid;                     // group-of-8 index
        int r = i >> 6, c = i & 63;
        const float4* src = (const float4*)(vin + (size_t)r * 1024 + c * 8);
        float4 f0 = src[0], f1 = src[1];
        float4* dst = (float4*)(vout + (size_t)r * 1024 + c * 8);
        dst[0] = f0; dst[1] = f1;
        union { __hip_bfloat16 h[8]; uint4 v; } u;
        u.h[0] = __float2bfloat16(f0.x - 0.5f); u.h[1] = __float2bfloat16(f0.y - 0.5f);
        u.h[2] = __float2bfloat16(f0.z - 0.5f); u.h[3] = __float2bfloat16(f0.w - 0.5f);
        u.h[4] = __float2bfloat16(f1.x - 0.5f); u.h[5] = __float2bfloat16(f1.y - 0.5f);
        u.h[6] = __float2bfloat16(f1.z - 0.5f); u.h[7] = __float2bfloat16(f1.w - 0.5f);
        *(uint4*)(Abf + (size_t)r * 512 + c * 8) = u.v;
        if (tid < 4) { int row = b * 4 + tid; ldout[row] = ld[row]; }
    }
}

// ------- GEMM1: h = tanh(Abf @ W1T^T + b1), 64x128 tiles, 512 blocks (2/CU) -------
__global__ __launch_bounds__(256, 4) void gemm1_kernel(
        const __hip_bfloat16* __restrict__ Abf,   // (8192,512) bf16, = v_p - 0.5
        const __hip_bfloat16* __restrict__ W1T,   // (512,512) [n][k] bf16
        const float* __restrict__ b1,
        __hip_bfloat16* __restrict__ hM) {        // (8192,512) bf16
    __shared__ short ldsA[64 * 32];               // 4 KB
    __shared__ short ldsB[128 * 32];              // 8 KB
    int tid = threadIdx.x;
    int lane = tid & 63;
    int wv = tid >> 6, wr = wv >> 1, wc = wv & 1;
    int q = lane >> 4, cx = lane & 15;
    int rowBase = blockIdx.y * 64;
    int colBase = blockIdx.x * 128;
    floatx4 acc[2][4] = {};

    for (int k0 = 0; k0 < HH; k0 += 32) {
        {   // A tile: 64 rows x 32 k = 256 chunks, 1 per thread
            int row = tid >> 2, kc = tid & 3;
            unsigned loff = __builtin_amdgcn_readfirstlane((unsigned)((tid & 192) * 16));
            gload_lds16(Abf + (size_t)(rowBase + row) * HH + k0 + kc * 8, (char*)ldsA + loff);
        }
        #pragma unroll
        for (int j = 0; j < 2; ++j) {   // B tile: 128 x 32 = 512 chunks
            int i = j * 256 + tid;
            int row = i >> 2, kc = i & 3;
            unsigned loff = __builtin_amdgcn_readfirstlane((unsigned)((j * 256 + (tid & 192)) * 16));
            gload_lds16(W1T + (size_t)(colBase + row) * HH + k0 + kc * 8, (char*)ldsB + loff);
        }
        __syncthreads();
        short8 a[2], b[4];
        #pragma unroll
        for (int mt = 0; mt < 2; ++mt)
            a[mt] = *(const short8*)(ldsA + (wr * 32 + mt * 16 + cx) * 32 + q * 8);
        #pragma unroll
        for (int nt = 0; nt < 4; ++nt)
            b[nt] = *(const short8*)(ldsB + (wc * 64 + nt * 16 + cx) * 32 + q * 8);
        #pragma unroll
        for (int mt = 0; mt < 2; ++mt)
            #pragma unroll
            for (int nt = 0; nt < 4; ++nt)
                acc[mt][nt] = __builtin_amdgcn_mfma_f32_16x16x32_bf16(a[mt], b[nt], acc[mt][nt], 0, 0, 0);
        __syncthreads();
    }

    float b1v[4];
    #pragma unroll
    for (int nt = 0; nt < 4; ++nt) b1v[nt] = b1[colBase + wc * 64 + nt * 16 + cx];
    #pragma unroll
    for (int mt = 0; mt < 2; ++mt)
        #pragma unroll
        for (int nt = 0; nt < 4; ++nt) {
            int col = colBase + wc * 64 + nt * 16 + cx;
            #pragma unroll
            for (int r = 0; r < 4; ++r) {
                int row = rowBase + wr * 32 + mt * 16 + q * 4 + r;  // C: col=lane&15, row=quad*4+reg
                hM[(size_t)row * HH + col] = __float2bfloat16(tanh_fast(acc[mt][nt][r] + b1v[nt]));
            }
        }
}

// ------- GEMM2 v2: 256x256 tile, BK=64, dbuf LDS (128 KiB), 4-phase interleave, -------
// ------- XOR-swizzled LDS (T2), setprio (T5), counted prefetch (T3/T4-lite).   -------
// 8 waves (2M x 4N): wave owns 128x64 of C -> acc[8][4]. Prefetch distance = 1 K-tile:
// stages during tile t write ONLY buffer (t+1)&1, never the compute buffer -> race-free.
// vmcnt(0)+barrier at tile start drains exactly that tile's 8 loads (nothing deeper is
// outstanding), then 4 phases of {8x ds_read_b128 | half-tile stage | s_barrier |
// setprio(1) 16x MFMA setprio(0) | s_barrier}.
// LDS swizzle (both sides, rule 21): chunk' = chunk ^ (row&7); global source is
// inverse-swizzled (constant per thread), LDS dest stays linear for global_load_lds.
__global__ __launch_bounds__(512, 2) void gemm2_kernel(
        const __hip_bfloat16* __restrict__ hM,    // (8192,512) bf16
        const __hip_bfloat16* __restrict__ W2T,   // (8192,512) [n][k] bf16
        const float* __restrict__ b2,             // (8192) fp32
        const float* __restrict__ vin,            // (8192,1024) fp32, active cols 512..1023
        float* __restrict__ vout,                 // (8192,1024) fp32
        float* __restrict__ ldout) {              // (8192) fp32, pre-initialized to ld
    __shared__ __align__(16) char smem[131072];   // A dbuf 64K @0, B dbuf 64K @65536
    int tid = threadIdx.x;
    int lane = tid & 63;
    int wv = tid >> 6;                            // 0..7
    int wr = wv >> 2, wc = wv & 3;                // 2M x 4N wave grid
    int q = lane >> 4, cx = lane & 15;

    // XCD swizzle: bid&7 -> XCD; each XCD gets 4 contiguous row panels x 32 col tiles
    int bid = blockIdx.x;                         // 0..1023
    int xcd = bid & 7, w = bid >> 3;
    int by = xcd * 4 + (w & 3);                   // 0..31
    int bx = w >> 2;                              // 0..31
    int rowBase = by * 256;
    int colBase = bx * 256;

    floatx4 acc[8][4] = {};

    // --- staging constants (per-thread, loop-invariant) ---
    // half-tile = 128 rows x 64 k = 1024 chunks of 16B; thread does chunks {tid, 512+tid}
    // chunk c -> row = c>>3 (j*64 + tid>>3), kc = c&7 (= tid&7). Inverse swizzle folds to
    // a constant per-thread k offset: (tid&7) ^ ((tid>>3)&7).
    int srow = tid >> 3;                          // 0..63
    int skw  = ((tid & 7) ^ (srow & 7)) << 3;     // swizzled k offset (elements)
    const __hip_bfloat16* gA0 = hM  + (size_t)(rowBase +       srow) * HH + skw;  // hf0 j0
    const __hip_bfloat16* gA1 = hM  + (size_t)(rowBase +  64 + srow) * HH + skw;  // hf0 j1
    const __hip_bfloat16* gA2 = hM  + (size_t)(rowBase + 128 + srow) * HH + skw;  // hf1 j0
    const __hip_bfloat16* gA3 = hM  + (size_t)(rowBase + 192 + srow) * HH + skw;  // hf1 j1
    const __hip_bfloat16* gB0 = W2T + (size_t)(colBase +       srow) * HH + skw;
    const __hip_bfloat16* gB1 = W2T + (size_t)(colBase +  64 + srow) * HH + skw;
    const __hip_bfloat16* gB2 = W2T + (size_t)(colBase + 128 + srow) * HH + skw;
    const __hip_bfloat16* gB3 = W2T + (size_t)(colBase + 192 + srow) * HH + skw;
    unsigned l0  = (unsigned)__builtin_amdgcn_readfirstlane((tid & 448) * 16);  // wave base
    unsigned lo0 = l0;                            // hf0 j0
    unsigned lo1 = l0 + 8192;                     // hf0 j1
    unsigned lo2 = l0 + 16384;                    // hf1 j0
    unsigned lo3 = l0 + 24576;                    // hf1 j1

    // --- prologue: stage K-tile 0 into buffer 0 ---
    {
        char* A0 = smem;
        char* B0 = smem + 65536;
        gload_lds16(gA0, A0 + lo0); gload_lds16(gA1, A0 + lo1);
        gload_lds16(gA2, A0 + lo2); gload_lds16(gA3, A0 + lo3);
        gload_lds16(gB0, B0 + lo0); gload_lds16(gB1, B0 + lo1);
        gload_lds16(gB2, B0 + lo2); gload_lds16(gB3, B0 + lo3);
    }

    for (int t = 0; t < 8; ++t) {
        const short* Ac = (const short*)(smem + (t & 1) * 32768);
        const short* Bc = (const short*)(smem + 65536 + (t & 1) * 32768);
        char* An = smem + ((t & 1) ^ 1) * 32768;
        char* Bn = smem + 65536 + ((t & 1) ^ 1) * 32768;
        int kn = (t + 1) * 64;                    // next tile's k offset (elements)

        // own stage loads for tile t are the only outstanding vmem -> this is NOT an
        // over-drain; barrier makes every wave's stage data visible to all.
        asm volatile("s_waitcnt vmcnt(0)" ::: "memory");
        __builtin_amdgcn_sched_barrier(0);
        __builtin_amdgcn_s_barrier();
        __builtin_amdgcn_sched_barrier(0);

        #pragma unroll
        for (int ph = 0; ph < 4; ++ph) {          // phase = (kk = ph>>1, m-half = ph&1)
            const int kk = ph >> 1, mh = ph & 1;
            short8 a[4], b[4];
            #pragma unroll
            for (int i = 0; i < 4; ++i) {
                int rowA = wr * 128 + (mh * 4 + i) * 16 + cx;
                a[i] = *(const short8*)(Ac + rowA * 64 + (((kk * 4 + q) ^ (cx & 7)) << 3));
            }
            #pragma unroll
            for (int nt = 0; nt < 4; ++nt) {
                int rowB = wc * 64 + nt * 16 + cx;
                b[nt] = *(const short8*)(Bc + rowB * 64 + (((kk * 4 + q) ^ (cx & 7)) << 3));
            }
            if (t < 7) {                          // prefetch next tile (other buffer only)
                if (ph == 0) {
                    gload_lds16(gA0 + kn, An + lo0); gload_lds16(gA1 + kn, An + lo1);
                    gload_lds16(gA2 + kn, An + lo2); gload_lds16(gA3 + kn, An + lo3);
                } else if (ph == 1) {
                    gload_lds16(gB0 + kn, Bn + lo0); gload_lds16(gB1 + kn, Bn + lo1);
                    gload_lds16(gB2 + kn, Bn + lo2); gload_lds16(gB3 + kn, Bn + lo3);
                }
            }
            __builtin_amdgcn_sched_barrier(0);    // pin phase interleave (keep waves lockstep)
            __builtin_amdgcn_s_barrier();
            __builtin_amdgcn_sched_barrier(0);
            __builtin_amdgcn_s_setprio(1);
            #pragma unroll
            for (int i = 0; i < 4; ++i)
                #pragma unroll
                for (int nt = 0; nt < 4; ++nt)
                    acc[mh * 4 + i][nt] = __builtin_amdgcn_mfma_f32_16x16x32_bf16(
                        a[i], b[nt], acc[mh * 4 + i][nt], 0, 0, 0);
            __builtin_amdgcn_s_setprio(0);
            __builtin_amdgcn_sched_barrier(0);
            __builtin_amdgcn_s_barrier();
            __builtin_amdgcn_sched_barrier(0);
        }
    }

    // --- epilogue: identical math to v1, remapped to 8 frags/wave ---
    float* ldsE = (float*)smem;                   // staging LDS dead; final barrier passed
    float* myTile = ldsE + wv * (16 * 68);        // wave-private 16x68 fp32 slab (34.8 KB tot)
    int rowL = lane & 15, gL = lane >> 4;
    float b2v[4];
    #pragma unroll
    for (int nt = 0; nt < 4; ++nt) b2v[nt] = b2[colBase + wc * 64 + nt * 16 + cx];

    #pragma unroll
    for (int m = 0; m < 8; ++m) {
        // write phase: C slab (16 rows x 64 cols) -> LDS, +b2 folded in
        #pragma unroll
        for (int nt = 0; nt < 4; ++nt)
            #pragma unroll
            for (int r = 0; r < 4; ++r)
                myTile[(q * 4 + r) * 68 + nt * 16 + cx] = acc[m][nt][r] + b2v[nt];
        // read phase: lane owns (row=rowL, group=gL): 16 contiguous floats
        floatx4 x0 = *(const floatx4*)(myTile + rowL * 68 + gL * 16);
        floatx4 x1 = *(const floatx4*)(myTile + rowL * 68 + gL * 16 + 4);
        floatx4 x2 = *(const floatx4*)(myTile + rowL * 68 + gL * 16 + 8);
        floatx4 x3 = *(const floatx4*)(myTile + rowL * 68 + gL * 16 + 12);
        float xs[16] = { x0[0],x0[1],x0[2],x0[3], x1[0],x1[1],x1[2],x1[3],
                         x2[0],x2[1],x2[2],x2[3], x3[0],x3[1],x3[2],x3[3] };

        int row  = rowBase + wr * 128 + m * 16 + rowL;
        int gAbs = bx * 16 + wc * 4 + gL;         // absolute h-group index (0..511)
        float v = vin[(size_t)row * 1024 + 512 + gAbs];
        int k = (int)ceilf(v * 16.0f) - 1;        // exact searchsorted('left')-1
        k = min(15, max(0, k));

        float s = 0.0f, csum = 0.0f, ek = 0.0f;
        #pragma unroll
        for (int j = 0; j < 16; ++j) {
            float e2 = __expf(2.0f * xs[j]);
            float tt = 1.0f - 2.0f * __builtin_amdgcn_rcpf(e2 + 1.0f);   // tanh
            float e  = __expf(tt);                // tt in [-1,1]: no max-subtract needed
            csum += (j < k)  ? e : 0.0f;
            ek    = (j == k) ? e : ek;
            s += e;
        }
        float rs = __builtin_amdgcn_rcpf(s);
        float pk  = ek * rs;
        float ylo = csum * rs;
        float alpha = (v - (float)k * WIDTH) * 16.0f;
        vout[(size_t)row * 1024 + 512 + gAbs] = ylo + alpha * pk;

        float logp = __logf(pk);
        logp += __shfl_xor(logp, 16, 64);         // reduce over 4 groups sharing a row
        logp += __shfl_xor(logp, 32, 64);
        if (lane < 16) atomicAdd(ldout + row, -logp);   // XCD-local panel
    }
}

extern "C" void kernel_launch(void* const* d_in, const int* in_sizes, int n_in,
                              void* d_out, int out_size, void* d_ws, size_t ws_size,
                              hipStream_t stream) {
    const float* vin = (const float*)d_in[0];
    const float* ld  = (const float*)d_in[1];
    const float* W1  = (const float*)d_in[2];
    const float* b1  = (const float*)d_in[3];
    const float* W2  = (const float*)d_in[4];
    const float* b2  = (const float*)d_in[5];
    float* vout  = (float*)d_out;
    float* ldout = vout + (size_t)BB * 1024;

    char* ws = (char*)d_ws;                                    // layout (16B aligned):
    __hip_bfloat16* Abf = (__hip_bfloat16*)(ws);               //  8 MB  @ 0
    __hip_bfloat16* W1T = (__hip_bfloat16*)(ws + 8388608);     //  0.5MB
    __hip_bfloat16* W2T = (__hip_bfloat16*)(ws + 8912896);     //  8 MB
    __hip_bfloat16* hM  = (__hip_bfloat16*)(ws + 17301504);    //  8 MB  (total ~24.5MB)

    prep_all<<<6400, 256, 0, stream>>>(vin, W1, W2, ld, vout, ldout, Abf, W1T, W2T);
    gemm1_kernel<<<dim3(4, 128), 256, 0, stream>>>(Abf, W1T, b1, hM);
    gemm2_kernel<<<1024, 512, 0, stream>>>(hM, W2T, b2, vin, vout, ldout);
}

// Round 2
// 202.986 us; speedup vs baseline: 1.0461x; 1.0461x over previous
//
#include <hip/hip_runtime.h>
#include <hip/hip_bf16.h>

#define HH   512
#define BB   8192
#define WIDTH (1.0f/16.0f)

typedef __attribute__((ext_vector_type(8))) short  short8;   // 8 bf16 = 4 VGPRs
typedef __attribute__((ext_vector_type(4))) float  floatx4;

typedef const __attribute__((address_space(1))) void* gptr_t;
typedef __attribute__((address_space(3))) void*       lptr_t;

__device__ __forceinline__ void gload_lds16(const void* g, void* l) {
    // async global->LDS, 16B per lane; LDS dst = wave-uniform base + lane*16
    __builtin_amdgcn_global_load_lds((gptr_t)g, (lptr_t)l, 16, 0, 0);
}

__device__ __forceinline__ float tanh_fast(float x) {
    float e = __expf(2.0f * x);
    return 1.0f - 2.0f * __builtin_amdgcn_rcpf(e + 1.0f);
}

// ---- prep_all: W2 transpose | W1 transpose | prep_v + ldout init, one dispatch ----
__global__ void prep_all(const float* __restrict__ vin, const float* __restrict__ W1,
                         const float* __restrict__ W2, const float* __restrict__ ld,
                         float* __restrict__ vout, float* __restrict__ ldout,
                         __hip_bfloat16* __restrict__ Abf,
                         __hip_bfloat16* __restrict__ W1T,
                         __hip_bfloat16* __restrict__ W2T) {
    __shared__ float tile[32][33];
    int bid = blockIdx.x, tid = threadIdx.x;
    if (bid < 4352) {
        // transpose branch: W2 (512x8192) for bid<4096, else W1 (512x512)
        const float* src;  __hip_bfloat16* dst;  int cols, c0, r0;
        if (bid < 4096) { src = W2; dst = W2T; cols = 8192; c0 = (bid & 255) * 32; r0 = (bid >> 8) * 32; }
        else            { int b = bid - 4096; src = W1; dst = W1T; cols = 512; c0 = (b & 15) * 32; r0 = (b >> 4) * 32; }
        int x = tid & 31, y = tid >> 5;            // (32,8) logical
        #pragma unroll
        for (int i = 0; i < 32; i += 8)
            tile[y + i][x] = src[(size_t)(r0 + y + i) * cols + c0 + x];
        __syncthreads();
        #pragma unroll
        for (int i = 0; i < 32; i += 8)
            dst[(size_t)(c0 + y + i) * 512 + r0 + x] = __float2bfloat16(tile[x][y + i]);
    } else {
        // prep_v branch: v_out[:, :512] = v_in[:, :512]; Abf = bf16(v_p - 0.5); ldout = ld
        int b = bid - 4352;                        // 0..2047
        int i = b * 256 + tid;                     // group-of-8 index
        int r = i >> 6, c = i & 63;
        const float4* src = (const float4*)(vin + (size_t)r * 1024 + c * 8);
        float4 f0 = src[0], f1 = src[1];
        float4* dst = (float4*)(vout + (size_t)r * 1024 + c * 8);
        dst[0] = f0; dst[1] = f1;
        union { __hip_bfloat16 h[8]; uint4 v; } u;
        u.h[0] = __float2bfloat16(f0.x - 0.5f); u.h[1] = __float2bfloat16(f0.y - 0.5f);
        u.h[2] = __float2bfloat16(f0.z - 0.5f); u.h[3] = __float2bfloat16(f0.w - 0.5f);
        u.h[4] = __float2bfloat16(f1.x - 0.5f); u.h[5] = __float2bfloat16(f1.y - 0.5f);
        u.h[6] = __float2bfloat16(f1.z - 0.5f); u.h[7] = __float2bfloat16(f1.w - 0.5f);
        *(uint4*)(Abf + (size_t)r * 512 + c * 8) = u.v;
        if (tid < 4) { int row = b * 4 + tid; ldout[row] = ld[row]; }
    }
}

// ------- GEMM1: h = tanh(Abf @ W1T^T + b1), 64x128 tiles, 512 blocks (2/CU) -------
// T2 swizzle: 16B chunk kc of row r sits at LDS slot kc^(r&3) (both sides: inverse-
// swizzled global source for linear global_load_lds dest + swizzled ds_read offset).
__global__ __launch_bounds__(256, 4) void gemm1_kernel(
        const __hip_bfloat16* __restrict__ Abf,   // (8192,512) bf16, = v_p - 0.5
        const __hip_bfloat16* __restrict__ W1T,   // (512,512) [n][k] bf16
        const float* __restrict__ b1,
        __hip_bfloat16* __restrict__ hM) {        // (8192,512) bf16
    __shared__ short ldsA[64 * 32];               // 4 KB
    __shared__ short ldsB[128 * 32];              // 8 KB
    int tid = threadIdx.x;
    int lane = tid & 63;
    int wv = tid >> 6, wr = wv >> 1, wc = wv & 1;
    int q = lane >> 4, cx = lane & 15;
    int qs = (q ^ (cx & 3)) * 8;                  // swizzled chunk offset for ds_read
    int kcs = ((tid & 3) ^ ((tid >> 2) & 3)) * 8; // inverse-swizzled k offset for staging
    int rowBase = blockIdx.y * 64;
    int colBase = blockIdx.x * 128;
    floatx4 acc[2][4] = {};

    for (int k0 = 0; k0 < HH; k0 += 32) {
        {   // A tile: 64 rows x 32 k = 256 chunks, 1 per thread
            int row = tid >> 2;
            unsigned loff = __builtin_amdgcn_readfirstlane((unsigned)((tid & 192) * 16));
            gload_lds16(Abf + (size_t)(rowBase + row) * HH + k0 + kcs, (char*)ldsA + loff);
        }
        #pragma unroll
        for (int j = 0; j < 2; ++j) {   // B tile: 128 x 32 = 512 chunks
            int i = j * 256 + tid;
            int row = i >> 2;
            unsigned loff = __builtin_amdgcn_readfirstlane((unsigned)((j * 256 + (tid & 192)) * 16));
            gload_lds16(W1T + (size_t)(colBase + row) * HH + k0 + kcs, (char*)ldsB + loff);
        }
        __syncthreads();
        short8 a[2], b[4];
        #pragma unroll
        for (int mt = 0; mt < 2; ++mt)
            a[mt] = *(const short8*)(ldsA + (wr * 32 + mt * 16 + cx) * 32 + qs);
        #pragma unroll
        for (int nt = 0; nt < 4; ++nt)
            b[nt] = *(const short8*)(ldsB + (wc * 64 + nt * 16 + cx) * 32 + qs);
        #pragma unroll
        for (int mt = 0; mt < 2; ++mt)
            #pragma unroll
            for (int nt = 0; nt < 4; ++nt)
                acc[mt][nt] = __builtin_amdgcn_mfma_f32_16x16x32_bf16(a[mt], b[nt], acc[mt][nt], 0, 0, 0);
        __syncthreads();
    }

    float b1v[4];
    #pragma unroll
    for (int nt = 0; nt < 4; ++nt) b1v[nt] = b1[colBase + wc * 64 + nt * 16 + cx];
    #pragma unroll
    for (int mt = 0; mt < 2; ++mt)
        #pragma unroll
        for (int nt = 0; nt < 4; ++nt) {
            int col = colBase + wc * 64 + nt * 16 + cx;
            #pragma unroll
            for (int r = 0; r < 4; ++r) {
                int row = rowBase + wr * 32 + mt * 16 + q * 4 + r;  // C: col=lane&15, row=quad*4+reg
                hM[(size_t)row * HH + col] = __float2bfloat16(tanh_fast(acc[mt][nt][r] + b1v[nt]));
            }
        }
}

// ------- GEMM2 fused: net=tanh(h@W2+b2); softmax(16); spline; atomic log-dens -------
// 16x16x32 MFMA, BK=64 (two stacked BK=32 tiles). XCD y-panel swizzle. T2 LDS swizzle
// (verified round 1: conflicts 9.4M -> 1.0M): chunk kc of row r at slot kc^(r&3).
__global__ __launch_bounds__(256, 4) void gemm2_kernel(
        const __hip_bfloat16* __restrict__ hM,    // (8192,512) bf16
        const __hip_bfloat16* __restrict__ W2T,   // (8192,512) [n][k] bf16
        const float* __restrict__ b2,             // (8192) fp32
        const float* __restrict__ vin,            // (8192,1024) fp32, active cols 512..1023
        float* __restrict__ vout,                 // (8192,1024) fp32
        float* __restrict__ ldout) {              // (8192) fp32, pre-initialized to ld
    __shared__ __align__(16) char smem[32768];    // A: 16K (2 halves), B: 16K; epilogue reuses
    short* ldsA = (short*)smem;
    short* ldsB = (short*)(smem + 16384);
    float* ldsE = (float*)smem;                   // epilogue: 4 waves x 16x68 fp32 (17408 B)
    int tid = threadIdx.x;
    int lane = tid & 63;
    int wv = tid >> 6, wr = wv >> 1, wc = wv & 1;
    int q = lane >> 4, cx = lane & 15;
    int qs = (q ^ (cx & 3)) * 8;                  // swizzled chunk offset for ds_read
    int kcs = ((tid & 3) ^ ((tid >> 2) & 3)) * 8; // inverse-swizzled k offset for staging
    // XCD swizzle: round-robin dispatch puts bid&7 on XCD (bid&7); give each XCD a
    // contiguous 8-block y-panel and iterate x within it.
    int bid = blockIdx.x;                         // 0..4095
    int xcd = bid & 7, w = bid >> 3;
    int by  = xcd * 8 + (w & 7);                  // y panel: 1024 rows per XCD
    int bx  = w >> 3;                             // 0..63
    int rowBase = by * 128;
    int colBase = bx * 128;
    floatx4 acc[4][4] = {};

    for (int k0 = 0; k0 < HH; k0 += 64) {
        #pragma unroll
        for (int j = 0; j < 4; ++j) {             // 1024 chunks per matrix: two BK=32 tiles
            int chunk = j * 256 + tid;
            int half  = j >> 1;
            int c2    = chunk & 511;
            int row = c2 >> 2;                    // row&3 == (tid>>2)&3, j-independent
            unsigned loff = __builtin_amdgcn_readfirstlane((unsigned)((j * 256 + (tid & 192)) * 16));
            gload_lds16(hM  + (size_t)(rowBase + row) * HH + k0 + half * 32 + kcs, (char*)ldsA + loff);
            gload_lds16(W2T + (size_t)(colBase + row) * HH + k0 + half * 32 + kcs, (char*)ldsB + loff);
        }
        __syncthreads();
        #pragma unroll
        for (int s = 0; s < 2; ++s) {             // sub-step: +8KB immediate offset
            const short* pA = ldsA + s * 4096;
            const short* pB = ldsB + s * 4096;
            short8 a[4], b[4];
            #pragma unroll
            for (int mt = 0; mt < 4; ++mt)
                a[mt] = *(const short8*)(pA + (wr * 64 + mt * 16 + cx) * 32 + qs);
            #pragma unroll
            for (int nt = 0; nt < 4; ++nt)
                b[nt] = *(const short8*)(pB + (wc * 64 + nt * 16 + cx) * 32 + qs);
            #pragma unroll
            for (int mt = 0; mt < 4; ++mt)
                #pragma unroll
                for (int nt = 0; nt < 4; ++nt)
                    acc[mt][nt] = __builtin_amdgcn_mfma_f32_16x16x32_bf16(a[mt], b[nt], acc[mt][nt], 0, 0, 0);
        }
        __syncthreads();   // staging LDS dead after last iter -> epilogue may reuse
    }

    float b2v[4];
    #pragma unroll
    for (int nt = 0; nt < 4; ++nt) b2v[nt] = b2[colBase + wc * 64 + nt * 16 + cx];

    float* myTile = ldsE + wv * (16 * 68);        // wave-private: no barrier needed
    int rowL  = lane & 15;                         // read-phase: lane's row within 16-row slab
    int gL    = lane >> 4;                         // lane's group (0..3) within wave's 64 cols
    int gAbs  = bx * 8 + wc * 4 + gL;             // absolute h-group index

    #pragma unroll
    for (int mt = 0; mt < 4; ++mt) {
        // write phase: C-layout slab (16 rows x 64 cols) -> LDS, +b2 folded in
        #pragma unroll
        for (int nt = 0; nt < 4; ++nt)
            #pragma unroll
            for (int r = 0; r < 4; ++r)
                myTile[(q * 4 + r) * 68 + nt * 16 + cx] = acc[mt][nt][r] + b2v[nt];
        // no __syncthreads: tile is wave-private; compiler inserts lgkmcnt wait

        // read phase: lane owns (row=rowL, group=gL): 16 contiguous floats
        floatx4 x0 = *(const floatx4*)(myTile + rowL * 68 + gL * 16);
        floatx4 x1 = *(const floatx4*)(myTile + rowL * 68 + gL * 16 + 4);
        floatx4 x2 = *(const floatx4*)(myTile + rowL * 68 + gL * 16 + 8);
        floatx4 x3 = *(const floatx4*)(myTile + rowL * 68 + gL * 16 + 12);
        float xs[16] = { x0[0],x0[1],x0[2],x0[3], x1[0],x1[1],x1[2],x1[3],
                         x2[0],x2[1],x2[2],x2[3], x3[0],x3[1],x3[2],x3[3] };

        int row = rowBase + wr * 64 + mt * 16 + rowL;
        float v = vin[(size_t)row * 1024 + 512 + gAbs];
        int k = (int)ceilf(v * 16.0f) - 1;        // exact searchsorted('left')-1 (v*16 exact)
        k = min(15, max(0, k));

        float s = 0.0f, csum = 0.0f, ek = 0.0f;
        #pragma unroll
        for (int j = 0; j < 16; ++j) {
            float e2 = __expf(2.0f * xs[j]);
            float t  = 1.0f - 2.0f * __builtin_amdgcn_rcpf(e2 + 1.0f);   // tanh
            float e  = __expf(t);                 // t in [-1,1]: no max-subtract needed
            csum += (j < k)  ? e : 0.0f;
            ek    = (j == k) ? e : ek;
            s += e;
        }
        float rs = __builtin_amdgcn_rcpf(s);
        float pk  = ek * rs;
        float ylo = csum * rs;
        float alpha = (v - (float)k * WIDTH) * 16.0f;
        vout[(size_t)row * 1024 + 512 + gAbs] = ylo + alpha * pk;

        float logp = __logf(pk);
        logp += __shfl_xor(logp, 16, 64);          // reduce over 4 groups sharing a row
        logp += __shfl_xor(logp, 32, 64);
        if (lane < 16) atomicAdd(ldout + row, -logp);   // XCD-local: row in this XCD's panel
    }
}

extern "C" void kernel_launch(void* const* d_in, const int* in_sizes, int n_in,
                              void* d_out, int out_size, void* d_ws, size_t ws_size,
                              hipStream_t stream) {
    const float* vin = (const float*)d_in[0];
    const float* ld  = (const float*)d_in[1];
    const float* W1  = (const float*)d_in[2];
    const float* b1  = (const float*)d_in[3];
    const float* W2  = (const float*)d_in[4];
    const float* b2  = (const float*)d_in[5];
    float* vout  = (float*)d_out;
    float* ldout = vout + (size_t)BB * 1024;

    char* ws = (char*)d_ws;                                    // layout (16B aligned):
    __hip_bfloat16* Abf = (__hip_bfloat16*)(ws);               //  8 MB  @ 0
    __hip_bfloat16* W1T = (__hip_bfloat16*)(ws + 8388608);     //  0.5MB
    __hip_bfloat16* W2T = (__hip_bfloat16*)(ws + 8912896);     //  8 MB
    __hip_bfloat16* hM  = (__hip_bfloat16*)(ws + 17301504);    //  8 MB  (total ~24.5MB)

    prep_all<<<6400, 256, 0, stream>>>(vin, W1, W2, ld, vout, ldout, Abf, W1T, W2T);
    gemm1_kernel<<<dim3(4, 128), 256, 0, stream>>>(Abf, W1T, b1, hM);
    gemm2_kernel<<<4096, 256, 0, stream>>>(hM, W2T, b2, vin, vout, ldout);
}

// Round 3
// 190.621 us; speedup vs baseline: 1.1140x; 1.0649x over previous
//
#include <hip/hip_runtime.h>
#include <hip/hip_bf16.h>

#define HH   512
#define BB   8192
#define WIDTH (1.0f/16.0f)

typedef __attribute__((ext_vector_type(8))) short  short8;   // 8 bf16 = 4 VGPRs
typedef __attribute__((ext_vector_type(4))) float  floatx4;

typedef const __attribute__((address_space(1))) void* gptr_t;
typedef __attribute__((address_space(3))) void*       lptr_t;

__device__ __forceinline__ void gload_lds16(const void* g, void* l) {
    // async global->LDS, 16B per lane; LDS dst = wave-uniform base + lane*16
    __builtin_amdgcn_global_load_lds((gptr_t)g, (lptr_t)l, 16, 0, 0);
}

__device__ __forceinline__ float tanh_fast(float x) {
    float e = __expf(2.0f * x);
    return 1.0f - 2.0f * __builtin_amdgcn_rcpf(e + 1.0f);
}

// ---- prep_all: W2 transpose | W1 transpose | prep_v + ldout init, one dispatch ----
// Transpose branch vectorized: float4 loads (single pass), ushort4 (8B) stores.
__global__ void prep_all(const float* __restrict__ vin, const float* __restrict__ W1,
                         const float* __restrict__ W2, const float* __restrict__ ld,
                         float* __restrict__ vout, float* __restrict__ ldout,
                         __hip_bfloat16* __restrict__ Abf,
                         __hip_bfloat16* __restrict__ W1T,
                         __hip_bfloat16* __restrict__ W2T) {
    __shared__ __align__(16) float tile[32 * 36];   // [k][n], stride 36 (row=144B, 16B-aligned)
    int bid = blockIdx.x, tid = threadIdx.x;
    if (bid < 4352) {
        // transpose branch: W2 (512x8192) for bid<4096, else W1 (512x512)
        const float* src;  __hip_bfloat16* dst;  int cols, c0, r0;
        if (bid < 4096) { src = W2; dst = W2T; cols = 8192; c0 = (bid & 255) * 32; r0 = (bid >> 8) * 32; }
        else            { int b = bid - 4096; src = W1; dst = W1T; cols = 512; c0 = (b & 15) * 32; r0 = (b >> 4) * 32; }
        int y  = tid >> 3;               // src row within tile (k), 0..31
        int x0 = (tid & 7) * 4;          // src col group (n)
        float4 v = *(const float4*)(src + (size_t)(r0 + y) * cols + c0 + x0);
        *(float4*)(tile + y * 36 + x0) = v;
        __syncthreads();
        int n  = tid >> 3;               // dst row (n), 0..31
        int k4 = (tid & 7) * 4;          // dst col group (k)
        union { __hip_bfloat16 h[4]; uint2 u; } o;
        o.h[0] = __float2bfloat16(tile[(k4 + 0) * 36 + n]);
        o.h[1] = __float2bfloat16(tile[(k4 + 1) * 36 + n]);
        o.h[2] = __float2bfloat16(tile[(k4 + 2) * 36 + n]);
        o.h[3] = __float2bfloat16(tile[(k4 + 3) * 36 + n]);
        *(uint2*)(dst + (size_t)(c0 + n) * 512 + r0 + k4) = o.u;
    } else {
        // prep_v branch: v_out[:, :512] = v_in[:, :512]; Abf = bf16(v_p - 0.5); ldout = ld
        int b = bid - 4352;                        // 0..2047
        int i = b * 256 + tid;                     // group-of-8 index
        int r = i >> 6, c = i & 63;
        const float4* src = (const float4*)(vin + (size_t)r * 1024 + c * 8);
        float4 f0 = src[0], f1 = src[1];
        float4* dst = (float4*)(vout + (size_t)r * 1024 + c * 8);
        dst[0] = f0; dst[1] = f1;
        union { __hip_bfloat16 h[8]; uint4 v; } u;
        u.h[0] = __float2bfloat16(f0.x - 0.5f); u.h[1] = __float2bfloat16(f0.y - 0.5f);
        u.h[2] = __float2bfloat16(f0.z - 0.5f); u.h[3] = __float2bfloat16(f0.w - 0.5f);
        u.h[4] = __float2bfloat16(f1.x - 0.5f); u.h[5] = __float2bfloat16(f1.y - 0.5f);
        u.h[6] = __float2bfloat16(f1.z - 0.5f); u.h[7] = __float2bfloat16(f1.w - 0.5f);
        *(uint4*)(Abf + (size_t)r * 512 + c * 8) = u.v;
        if (tid < 4) { int row = b * 4 + tid; ldout[row] = ld[row]; }
    }
}

// ------- GEMM1: h = tanh(Abf @ W1T^T + b1), 128x128 tiles, BK=64, grid (4,64) -------
// LDS [128][64] rows of 128B; 8-slot XOR swizzle (chunk kc of row r at slot kc^(r&7));
// inverse-swizzled global source keeps global_load_lds dest linear (rule 21).
__global__ __launch_bounds__(256, 4) void gemm1_kernel(
        const __hip_bfloat16* __restrict__ Abf,   // (8192,512) bf16, = v_p - 0.5
        const __hip_bfloat16* __restrict__ W1T,   // (512,512) [n][k] bf16
        const float* __restrict__ b1,
        __hip_bfloat16* __restrict__ hM) {        // (8192,512) bf16
    __shared__ __align__(16) char smem[32768];
    short* ldsA = (short*)smem;                   // [128][64] shorts, 16 KB
    short* ldsB = (short*)(smem + 16384);         // [128][64] shorts, 16 KB
    int tid = threadIdx.x;
    int lane = tid & 63;
    int wv = tid >> 6, wr = wv >> 1, wc = wv & 1;
    int q = lane >> 4, cx = lane & 15;
    int srow = tid >> 3;                          // staging row 0..31 (+j*32)
    int skw  = ((tid & 7) ^ (srow & 7)) * 8;      // inverse-swizzled k offset (elements)
    int rowBase = blockIdx.y * 128;
    int colBase = blockIdx.x * 128;
    floatx4 acc[4][4] = {};

    for (int k0 = 0; k0 < HH; k0 += 64) {
        #pragma unroll
        for (int j = 0; j < 4; ++j) {             // 1024 chunks per matrix
            int row = j * 32 + srow;
            unsigned loff = __builtin_amdgcn_readfirstlane((unsigned)((j * 256 + (tid & 192)) * 16));
            gload_lds16(Abf + (size_t)(rowBase + row) * HH + k0 + skw, (char*)ldsA + loff);
            gload_lds16(W1T + (size_t)(colBase + row) * HH + k0 + skw, (char*)ldsB + loff);
        }
        __syncthreads();
        #pragma unroll
        for (int s = 0; s < 2; ++s) {             // logical k-chunk = s*4+q, slot = ^(row&7)
            short8 a[4], b[4];
            #pragma unroll
            for (int mt = 0; mt < 4; ++mt)
                a[mt] = *(const short8*)(ldsA + (wr * 64 + mt * 16 + cx) * 64
                                              + (((s * 4 + q) ^ (cx & 7)) << 3));
            #pragma unroll
            for (int nt = 0; nt < 4; ++nt)
                b[nt] = *(const short8*)(ldsB + (wc * 64 + nt * 16 + cx) * 64
                                              + (((s * 4 + q) ^ (cx & 7)) << 3));
            #pragma unroll
            for (int mt = 0; mt < 4; ++mt)
                #pragma unroll
                for (int nt = 0; nt < 4; ++nt)
                    acc[mt][nt] = __builtin_amdgcn_mfma_f32_16x16x32_bf16(a[mt], b[nt], acc[mt][nt], 0, 0, 0);
        }
        __syncthreads();
    }

    float b1v[4];
    #pragma unroll
    for (int nt = 0; nt < 4; ++nt) b1v[nt] = b1[colBase + wc * 64 + nt * 16 + cx];
    #pragma unroll
    for (int mt = 0; mt < 4; ++mt)
        #pragma unroll
        for (int nt = 0; nt < 4; ++nt) {
            int col = colBase + wc * 64 + nt * 16 + cx;
            #pragma unroll
            for (int r = 0; r < 4; ++r) {
                int row = rowBase + wr * 64 + mt * 16 + q * 4 + r;  // C: col=lane&15, row=quad*4+reg
                hM[(size_t)row * HH + col] = __float2bfloat16(tanh_fast(acc[mt][nt][r] + b1v[nt]));
            }
        }
}

// ------- GEMM2 fused: net=tanh(h@W2+b2); softmax(16); spline; atomic log-dens -------
// v0 structure (tile/barriers/occupancy untouched). LDS geometry changed: [128][64]
// rows of 128B + 8-slot XOR swizzle -> quarter-wave 2-way (free) on ds_read_b128.
// Epilogue slab stride 68 -> 76 floats (read-phase 4-way -> 2-way).
__global__ __launch_bounds__(256, 4) void gemm2_kernel(
        const __hip_bfloat16* __restrict__ hM,    // (8192,512) bf16
        const __hip_bfloat16* __restrict__ W2T,   // (8192,512) [n][k] bf16
        const float* __restrict__ b2,             // (8192) fp32
        const float* __restrict__ vin,            // (8192,1024) fp32, active cols 512..1023
        float* __restrict__ vout,                 // (8192,1024) fp32
        float* __restrict__ ldout) {              // (8192) fp32, pre-initialized to ld
    __shared__ __align__(16) char smem[32768];    // A: 16K, B: 16K; epilogue reuses
    short* ldsA = (short*)smem;                   // [128][64] shorts
    short* ldsB = (short*)(smem + 16384);         // [128][64] shorts
    float* ldsE = (float*)smem;                   // epilogue: 4 waves x 16x76 fp32 (19456 B)
    int tid = threadIdx.x;
    int lane = tid & 63;
    int wv = tid >> 6, wr = wv >> 1, wc = wv & 1;
    int q = lane >> 4, cx = lane & 15;
    int srow = tid >> 3;                          // staging row 0..31 (+j*32)
    int skw  = ((tid & 7) ^ (srow & 7)) * 8;      // inverse-swizzled k offset (elements)
    // XCD swizzle: round-robin dispatch puts bid&7 on XCD (bid&7); give each XCD a
    // contiguous 8-block y-panel and iterate x within it.
    int bid = blockIdx.x;                         // 0..4095
    int xcd = bid & 7, w = bid >> 3;
    int by  = xcd * 8 + (w & 7);                  // y panel: 1024 rows per XCD
    int bx  = w >> 3;                             // 0..63
    int rowBase = by * 128;
    int colBase = bx * 128;
    floatx4 acc[4][4] = {};

    for (int k0 = 0; k0 < HH; k0 += 64) {
        #pragma unroll
        for (int j = 0; j < 4; ++j) {             // 1024 chunks per matrix
            int row = j * 32 + srow;
            unsigned loff = __builtin_amdgcn_readfirstlane((unsigned)((j * 256 + (tid & 192)) * 16));
            gload_lds16(hM  + (size_t)(rowBase + row) * HH + k0 + skw, (char*)ldsA + loff);
            gload_lds16(W2T + (size_t)(colBase + row) * HH + k0 + skw, (char*)ldsB + loff);
        }
        __syncthreads();
        #pragma unroll
        for (int s = 0; s < 2; ++s) {             // logical k-chunk = s*4+q, slot = ^(row&7)
            short8 a[4], b[4];
            #pragma unroll
            for (int mt = 0; mt < 4; ++mt)
                a[mt] = *(const short8*)(ldsA + (wr * 64 + mt * 16 + cx) * 64
                                              + (((s * 4 + q) ^ (cx & 7)) << 3));
            #pragma unroll
            for (int nt = 0; nt < 4; ++nt)
                b[nt] = *(const short8*)(ldsB + (wc * 64 + nt * 16 + cx) * 64
                                              + (((s * 4 + q) ^ (cx & 7)) << 3));
            #pragma unroll
            for (int mt = 0; mt < 4; ++mt)
                #pragma unroll
                for (int nt = 0; nt < 4; ++nt)
                    acc[mt][nt] = __builtin_amdgcn_mfma_f32_16x16x32_bf16(a[mt], b[nt], acc[mt][nt], 0, 0, 0);
        }
        __syncthreads();   // staging LDS dead after last iter -> epilogue may reuse
    }

    float b2v[4];
    #pragma unroll
    for (int nt = 0; nt < 4; ++nt) b2v[nt] = b2[colBase + wc * 64 + nt * 16 + cx];

    float* myTile = ldsE + wv * (16 * 76);        // wave-private: no barrier needed
    int rowL  = lane & 15;                         // read-phase: lane's row within 16-row slab
    int gL    = lane >> 4;                         // lane's group (0..3) within wave's 64 cols
    int gAbs  = bx * 8 + wc * 4 + gL;             // absolute h-group index

    #pragma unroll
    for (int mt = 0; mt < 4; ++mt) {
        // write phase: C-layout slab (16 rows x 64 cols) -> LDS, +b2 folded in
        #pragma unroll
        for (int nt = 0; nt < 4; ++nt)
            #pragma unroll
            for (int r = 0; r < 4; ++r)
                myTile[(q * 4 + r) * 76 + nt * 16 + cx] = acc[mt][nt][r] + b2v[nt];
        // no __syncthreads: tile is wave-private; compiler inserts lgkmcnt wait

        // read phase: lane owns (row=rowL, group=gL): 16 contiguous floats
        floatx4 x0 = *(const floatx4*)(myTile + rowL * 76 + gL * 16);
        floatx4 x1 = *(const floatx4*)(myTile + rowL * 76 + gL * 16 + 4);
        floatx4 x2 = *(const floatx4*)(myTile + rowL * 76 + gL * 16 + 8);
        floatx4 x3 = *(const floatx4*)(myTile + rowL * 76 + gL * 16 + 12);
        float xs[16] = { x0[0],x0[1],x0[2],x0[3], x1[0],x1[1],x1[2],x1[3],
                         x2[0],x2[1],x2[2],x2[3], x3[0],x3[1],x3[2],x3[3] };

        int row = rowBase + wr * 64 + mt * 16 + rowL;
        float v = vin[(size_t)row * 1024 + 512 + gAbs];
        int k = (int)ceilf(v * 16.0f) - 1;        // exact searchsorted('left')-1 (v*16 exact)
        k = min(15, max(0, k));

        float s = 0.0f, csum = 0.0f, ek = 0.0f;
        #pragma unroll
        for (int j = 0; j < 16; ++j) {
            float e2 = __expf(2.0f * xs[j]);
            float t  = 1.0f - 2.0f * __builtin_amdgcn_rcpf(e2 + 1.0f);   // tanh
            float e  = __expf(t);                 // t in [-1,1]: no max-subtract needed
            csum += (j < k)  ? e : 0.0f;
            ek    = (j == k) ? e : ek;
            s += e;
        }
        float rs = __builtin_amdgcn_rcpf(s);
        float pk  = ek * rs;
        float ylo = csum * rs;
        float alpha = (v - (float)k * WIDTH) * 16.0f;
        vout[(size_t)row * 1024 + 512 + gAbs] = ylo + alpha * pk;

        float logp = __logf(pk);
        logp += __shfl_xor(logp, 16, 64);          // reduce over 4 groups sharing a row
        logp += __shfl_xor(logp, 32, 64);
        if (lane < 16) atomicAdd(ldout + row, -logp);   // XCD-local: row in this XCD's panel
    }
}

extern "C" void kernel_launch(void* const* d_in, const int* in_sizes, int n_in,
                              void* d_out, int out_size, void* d_ws, size_t ws_size,
                              hipStream_t stream) {
    const float* vin = (const float*)d_in[0];
    const float* ld  = (const float*)d_in[1];
    const float* W1  = (const float*)d_in[2];
    const float* b1  = (const float*)d_in[3];
    const float* W2  = (const float*)d_in[4];
    const float* b2  = (const float*)d_in[5];
    float* vout  = (float*)d_out;
    float* ldout = vout + (size_t)BB * 1024;

    char* ws = (char*)d_ws;                                    // layout (16B aligned):
    __hip_bfloat16* Abf = (__hip_bfloat16*)(ws);               //  8 MB  @ 0
    __hip_bfloat16* W1T = (__hip_bfloat16*)(ws + 8388608);     //  0.5MB
    __hip_bfloat16* W2T = (__hip_bfloat16*)(ws + 8912896);     //  8 MB
    __hip_bfloat16* hM  = (__hip_bfloat16*)(ws + 17301504);    //  8 MB  (total ~24.5MB)

    prep_all<<<6400, 256, 0, stream>>>(vin, W1, W2, ld, vout, ldout, Abf, W1T, W2T);
    gemm1_kernel<<<dim3(4, 64), 256, 0, stream>>>(Abf, W1T, b1, hM);
    gemm2_kernel<<<4096, 256, 0, stream>>>(hM, W2T, b2, vin, vout, ldout);
}